// Round 8
// baseline (3012.305 us; speedup 1.0000x reference)
//
#include <hip/hip_runtime.h>

#define NGRAPH 512
#define NNODE  128
#define NEDGE  512
#define EMB    300
#define NLAYER 5
#define FA     9
#define FB     3
#define VV     64
#define KPAD   136   // padded K stride (bf16 elems) for A / xT tiles

typedef __bf16 bf16x8 __attribute__((ext_vector_type(8)));
typedef __bf16 bf16x4 __attribute__((ext_vector_type(4)));
typedef float  f32x4  __attribute__((ext_vector_type(4)));

__device__ __forceinline__ void gload_lds16(const void* gptr, void* lptr) {
    __builtin_amdgcn_global_load_lds(
        (const __attribute__((address_space(1))) void*)gptr,
        (__attribute__((address_space(3))) void*)lptr, 16, 0, 0);
}

// ---------------------------------------------------------------------------
// Kernel 0: weight prep — transpose w1/w2 to bf16 [N][K] (padded, zeros).
// ---------------------------------------------------------------------------
__global__ __launch_bounds__(256)
void prep_w_kernel(const float* __restrict__ w1, const float* __restrict__ w2,
                   __bf16* __restrict__ w1t, __bf16* __restrict__ w2t)
{
    const int i = blockIdx.x * 256 + threadIdx.x;
    const int T1 = NLAYER * 640 * 320;
    const int T2 = NLAYER * 320 * 640;
    if (i < T1) {
        const int l = i / (640 * 320);
        const int r = i - l * 640 * 320;
        const int n = r / 320, k = r - n * 320;
        float v = (n < 600 && k < 300) ? w1[((size_t)l * 300 + k) * 600 + n] : 0.f;
        w1t[i] = (__bf16)v;
    } else if (i < T1 + T2) {
        const int j = i - T1;
        const int l = j / (320 * 640);
        const int r = j - l * 320 * 640;
        const int n = r / 640, k = r - n * 640;
        float v = (n < 300 && k < 600) ? w2[((size_t)l * 600 + k) * 300 + n] : 0.f;
        w2t[j] = (__bf16)v;
    }
}

// ---------------------------------------------------------------------------
// Kernel 1a: adjacency build (unchanged)
// ---------------------------------------------------------------------------
__global__ __launch_bounds__(512)
void adj_kernel(const int* __restrict__ edge_index,
                const int* __restrict__ edge_attr,
                const float* __restrict__ bond_tab_root,
                const float* __restrict__ edge_lin_w,
                const float* __restrict__ edge_lin_b,
                __bf16* __restrict__ Ahi_g, __bf16* __restrict__ Alo_g)
{
    __shared__ float A[128 * 129];
    __shared__ float ew_s[NEDGE];
    __shared__ int   es[NEDGE];
    __shared__ float rinv[128];
    __shared__ float cinv[128];

    const int tid = threadIdx.x;
    const int g   = blockIdx.x;
    int* Ai = (int*)A;

    for (int e = tid; e < NEDGE; e += 512) {
        int r = edge_index[(g * 2 + 0) * NEDGE + e];
        int c = edge_index[(g * 2 + 1) * NEDGE + e];
        es[e] = r | (c << 8);
    }
    for (int i = tid; i < 128 * 129; i += 512) Ai[i] = -1;
    __syncthreads();

    {
        const int wave = tid >> 6, lane = tid & 63;
        const float elb = edge_lin_b[0];
        for (int e = wave * 64; e < wave * 64 + 64; ++e) {
            const int base = (g * NEDGE + e) * 3;
            const int a0 = edge_attr[base + 0];
            const int a1 = edge_attr[base + 1];
            const int a2 = edge_attr[base + 2];
            const float* t0 = bond_tab_root + (0 * VV + a0) * EMB;
            const float* t1 = bond_tab_root + (1 * VV + a1) * EMB;
            const float* t2 = bond_tab_root + (2 * VV + a2) * EMB;
            float acc = 0.f;
            for (int d = lane; d < EMB; d += 64)
                acc += (t0[d] + t1[d] + t2[d]) * edge_lin_w[d];
            #pragma unroll
            for (int off = 32; off > 0; off >>= 1) acc += __shfl_xor(acc, off, 64);
            if (lane == 0) ew_s[e] = 1.f / (1.f + expf(-(acc + elb)));
        }
    }
    for (int e = tid; e < NEDGE; e += 512) {
        int r = es[e] & 255, c = es[e] >> 8;
        atomicMax(&Ai[r * 129 + c], e);
        atomicMax(&Ai[c * 129 + r], 512 + e);
    }
    __syncthreads();
    for (int i = tid; i < 128 * 129; i += 512) {
        int p = Ai[i];
        A[i] = (p < 0) ? 0.f : ew_s[p & 511];
    }
    __syncthreads();
    if (tid < 128) A[tid * 129 + tid] += 1.f;
    __syncthreads();
    if (tid < 128) {
        float rs = 0.f, cs = 0.f;
        for (int j = 0; j < 128; ++j) { rs += A[tid * 129 + j]; cs += A[j * 129 + tid]; }
        rinv[tid] = 1.f / sqrtf(rs);
        cinv[tid] = 1.f / sqrtf(cs);
    }
    __syncthreads();
    for (int i = tid; i < 128 * KPAD; i += 512) {
        const int m = i / KPAD, k = i - m * KPAD;
        float v = (k < 128) ? A[m * 129 + k] * cinv[m] * rinv[k] : 0.f;
        __bf16 hi = (__bf16)v;
        Ahi_g[(size_t)g * 128 * KPAD + i] = hi;
        Alo_g[(size_t)g * 128 * KPAD + i] = (__bf16)(v - (float)hi);
    }
}

// ---------------------------------------------------------------------------
// Kernel 1b: diffusion via MFMA with split-bf16 (unchanged)
// ---------------------------------------------------------------------------
__global__ __launch_bounds__(512)
void diffuse_mm_kernel(const int* __restrict__ order_p,
                       const int* __restrict__ x_atom,
                       const float* __restrict__ atom_tab,
                       const __bf16* __restrict__ Ahi_g,
                       const __bf16* __restrict__ Alo_g,
                       float* __restrict__ h)
{
    __shared__ __bf16 Ahi[128 * KPAD];
    __shared__ __bf16 Alo[128 * KPAD];
    __shared__ __bf16 xt[4 * 64 * KPAD];
    __shared__ int    xat[128 * FA];

    const int tid  = threadIdx.x;
    const int g    = blockIdx.x;
    const int lane = tid & 63;
    const int wid  = tid >> 6;
    const int wm   = (wid >> 1) * 32;
    const int wn   = (wid & 1) * 32;
    const int lr   = lane & 15;
    const int q4   = (lane >> 4) * 4;
    const int kc   = (lane >> 4) * 8;

    for (int idx = tid; idx < 128 * KPAD / 8; idx += 512) {
        gload_lds16(Ahi_g + (size_t)g * 128 * KPAD + idx * 8, (char*)Ahi + idx * 16);
        gload_lds16(Alo_g + (size_t)g * 128 * KPAD + idx * 8, (char*)Alo + idx * 16);
    }
    for (int i = tid; i < 128 * FA; i += 512) xat[i] = x_atom[g * 128 * FA + i];
    __syncthreads();

    const int   ord    = order_p[0];
    const float yscale = 1.f / (float)(ord + 1);

    for (int cb = 0; cb < 5; ++cb) {
        const int dbase = cb * 64;

        float yacc[2][2][4];
        #pragma unroll
        for (int mi = 0; mi < 2; ++mi) {
            #pragma unroll
            for (int ni = 0; ni < 2; ++ni) {
                const int n_ = wn + ni * 16 + lr;
                const int d  = dbase + n_;
                #pragma unroll
                for (int r = 0; r < 4; ++r) {
                    const int m_ = wm + mi * 16 + q4 + r;
                    float v = 0.f;
                    if (d < EMB) {
                        #pragma unroll
                        for (int f = 0; f < FA; ++f)
                            v += atom_tab[(size_t)((f << 6) + xat[m_ * FA + f]) * EMB + d];
                        v *= 0.8f;
                    }
                    yacc[mi][ni][r] = v;
                    __bf16 hi = (__bf16)v;
                    xt[0 * 64 * KPAD + n_ * KPAD + m_] = hi;
                    xt[1 * 64 * KPAD + n_ * KPAD + m_] = (__bf16)(v - (float)hi);
                }
            }
        }
        __syncthreads();

        int curbuf = 0;
        for (int o = 0; o < ord; ++o) {
            const __bf16* xh = xt + (curbuf * 2 + 0) * 64 * KPAD;
            const __bf16* xl = xt + (curbuf * 2 + 1) * 64 * KPAD;
            f32x4 racc[2][2];
            #pragma unroll
            for (int mi = 0; mi < 2; ++mi)
                #pragma unroll
                for (int ni = 0; ni < 2; ++ni) racc[mi][ni] = (f32x4){0.f, 0.f, 0.f, 0.f};

            #pragma unroll
            for (int ks = 0; ks < 4; ++ks) {
                const int k0 = ks * 32 + kc;
                bf16x8 ah[2], al[2], bh[2], bl[2];
                #pragma unroll
                for (int mi = 0; mi < 2; ++mi) {
                    ah[mi] = *(const bf16x8*)&Ahi[(wm + mi * 16 + lr) * KPAD + k0];
                    al[mi] = *(const bf16x8*)&Alo[(wm + mi * 16 + lr) * KPAD + k0];
                }
                #pragma unroll
                for (int ni = 0; ni < 2; ++ni) {
                    bh[ni] = *(const bf16x8*)&xh[(wn + ni * 16 + lr) * KPAD + k0];
                    bl[ni] = *(const bf16x8*)&xl[(wn + ni * 16 + lr) * KPAD + k0];
                }
                #pragma unroll
                for (int mi = 0; mi < 2; ++mi) {
                    #pragma unroll
                    for (int ni = 0; ni < 2; ++ni) {
                        racc[mi][ni] = __builtin_amdgcn_mfma_f32_16x16x32_bf16(
                            ah[mi], bh[ni], racc[mi][ni], 0, 0, 0);
                        racc[mi][ni] = __builtin_amdgcn_mfma_f32_16x16x32_bf16(
                            ah[mi], bl[ni], racc[mi][ni], 0, 0, 0);
                        racc[mi][ni] = __builtin_amdgcn_mfma_f32_16x16x32_bf16(
                            al[mi], bh[ni], racc[mi][ni], 0, 0, 0);
                    }
                }
            }

            __bf16* nh = xt + ((curbuf ^ 1) * 2 + 0) * 64 * KPAD;
            __bf16* nl = xt + ((curbuf ^ 1) * 2 + 1) * 64 * KPAD;
            #pragma unroll
            for (int mi = 0; mi < 2; ++mi) {
                #pragma unroll
                for (int ni = 0; ni < 2; ++ni) {
                    const int n_ = wn + ni * 16 + lr;
                    const int mbase = wm + mi * 16 + q4;
                    bf16x4 hv, lv;
                    #pragma unroll
                    for (int r = 0; r < 4; ++r) {
                        const float v = racc[mi][ni][r];
                        yacc[mi][ni][r] += v;
                        __bf16 hi = (__bf16)v;
                        hv[r] = hi;
                        lv[r] = (__bf16)(v - (float)hi);
                    }
                    *(bf16x4*)&nh[n_ * KPAD + mbase] = hv;
                    *(bf16x4*)&nl[n_ * KPAD + mbase] = lv;
                }
            }
            __syncthreads();
            curbuf ^= 1;
        }

        #pragma unroll
        for (int mi = 0; mi < 2; ++mi) {
            #pragma unroll
            for (int ni = 0; ni < 2; ++ni) {
                const int n_ = wn + ni * 16 + lr;
                const int d  = dbase + n_;
                if (d < EMB) {
                    #pragma unroll
                    for (int r = 0; r < 4; ++r) {
                        const int m_ = wm + mi * 16 + q4 + r;
                        h[(size_t)(g * 128 + m_) * EMB + d] = yacc[mi][ni][r] * yscale;
                    }
                }
            }
        }
    }
}

// ---------------------------------------------------------------------------
// Kernel 2: GIN aggregation, EDGE-PARALLEL with LDS fp32 atomics.
// One block (1024 thr, 16 waves) per graph. No CSR: wave w owns edges
// e = w, w+16, ... (independent iterations -> loads fully pipelined).
// ag seeded with (1+eps)h at staging; msg = relu(hs[src]+ee) atomicAdd'd
// into ag[dst]. Two dim-halves of 150.
// ---------------------------------------------------------------------------
__global__ __launch_bounds__(1024)
void agg_kernel(const int* __restrict__ edge_index,
                const int* __restrict__ edge_attr,
                const float* __restrict__ bond_tabs,
                const float* __restrict__ eps_all,
                const int l,
                float* __restrict__ h)
{
    __shared__ float hs[128 * 152];   // 77,824 B snapshot
    __shared__ float ag[128 * 152];   // 77,824 B accumulator
    __shared__ int   epk[NEDGE];      // src | dst<<7 | a0<<14 | a1<<20 | a2<<26

    const int tid  = threadIdx.x;
    const int g    = blockIdx.x;
    const int wave = tid >> 6, lane = tid & 63;
    const float epl = 1.f + eps_all[l];
    const float* bt = bond_tabs + (size_t)l * FB * VV * EMB;

    if (tid < NEDGE) {
        const int s_ = edge_index[(g * 2 + 0) * NEDGE + tid];
        const int d_ = edge_index[(g * 2 + 1) * NEDGE + tid];
        const int base = (g * NEDGE + tid) * 3;
        epk[tid] = s_ | (d_ << 7) | (edge_attr[base + 0] << 14)
                 | (edge_attr[base + 1] << 20) | (edge_attr[base + 2] << 26);
    }

    for (int half = 0; half < 2; ++half) {
        const int doff = half * 150;
        __syncthreads();   // epk ready (half 0) / prev half writeback done
        for (int idx = tid; idx < 128 * 150; idx += 1024) {
            const int i = idx / 150, d = idx - i * 150;
            const float v = h[(size_t)(g * 128 + i) * EMB + doff + d];
            hs[i * 152 + d] = v;
            ag[i * 152 + d] = epl * v;
        }
        __syncthreads();
        for (int e = wave; e < NEDGE; e += 16) {
            const int p   = epk[e];
            const int src = p & 127;
            const int dst = (p >> 7) & 127;
            const float* t0 = bt + ((p >> 14) & 63) * EMB + doff;
            const float* t1 = bt + (64  + ((p >> 20) & 63)) * EMB + doff;
            const float* t2 = bt + (128 + ((p >> 26) & 63)) * EMB + doff;
            {
                const int d = lane;
                const float m = fmaxf(hs[src * 152 + d] + t0[d] + t1[d] + t2[d], 0.f);
                atomicAdd(&ag[dst * 152 + d], m);
            }
            {
                const int d = lane + 64;
                const float m = fmaxf(hs[src * 152 + d] + t0[d] + t1[d] + t2[d], 0.f);
                atomicAdd(&ag[dst * 152 + d], m);
            }
            if (lane < 22) {
                const int d = lane + 128;
                const float m = fmaxf(hs[src * 152 + d] + t0[d] + t1[d] + t2[d], 0.f);
                atomicAdd(&ag[dst * 152 + d], m);
            }
        }
        __syncthreads();
        for (int idx = tid; idx < 128 * 150; idx += 1024) {
            const int i = idx / 150, d = idx - i * 150;
            h[(size_t)(g * 128 + i) * EMB + doff + d] = ag[i * 152 + d];
        }
    }
}

// ---------------------------------------------------------------------------
// Kernel 3: bf16 MFMA GEMM with XCD-chunk swizzle (unchanged from round 6).
// ---------------------------------------------------------------------------
template <int ABF16, int CBF16, int RELU>
__global__ __launch_bounds__(256)
void gemm_mfma(const void* __restrict__ Av, const int lda, const int Kreal,
               const int nT, const int nBlkN, const __bf16* __restrict__ B,
               void* __restrict__ Cv, const int ldc, const int Nreal,
               const float* __restrict__ bias, const float* __restrict__ gam,
               const float* __restrict__ bet)
{
    __shared__ unsigned short As[128 * 32];
    __shared__ unsigned short Bs[64 * 32];

    const int tid  = threadIdx.x;
    const int nwg  = gridDim.x;
    const int hw   = blockIdx.x;
    const int lg   = (hw & 7) * (nwg >> 3) + (hw >> 3);
    const int bn   = (lg % nBlkN) * 64;
    const int bm   = (lg / nBlkN) * 128;
    const int wid  = tid >> 6;
    const int lane = tid & 63;
    const int wm   = (wid >> 1) * 64;
    const int wn   = (wid & 1) * 32;
    const int lr   = lane & 15;
    const int kc   = (lane >> 4) * 8;
    const int KP   = nT * 32;

    f32x4 acc[4][2];
    #pragma unroll
    for (int mi = 0; mi < 4; ++mi)
        #pragma unroll
        for (int ni = 0; ni < 2; ++ni) acc[mi][ni] = (f32x4){0.f, 0.f, 0.f, 0.f};

    for (int t = 0; t < nT; ++t) {
        const int k0 = t * 32;
        {
            const int n = tid >> 2, k8 = (tid & 3) * 8;
            gload_lds16(B + (size_t)(bn + n) * KP + k0 + k8,
                        (char*)Bs + tid * 16);
        }
        if (ABF16) {
            const __bf16* A = (const __bf16*)Av;
            #pragma unroll
            for (int q = 0; q < 2; ++q) {
                const int idx = q * 256 + tid;
                const int m = idx >> 2, k8 = (idx & 3) * 8;
                gload_lds16(A + (size_t)(bm + m) * lda + k0 + k8,
                            (char*)As + idx * 16);
            }
        } else {
            const float* A = (const float*)Av;
            #pragma unroll
            for (int q = 0; q < 2; ++q) {
                const int idx = q * 256 + tid;
                const int m = idx >> 2;
                const int k = k0 + (idx & 3) * 8;
                const float* src = A + (size_t)(bm + m) * lda + k;
                float v[8];
                if (k + 7 < Kreal) {
                    const float4 u0 = *(const float4*)src;
                    const float4 u1 = *(const float4*)(src + 4);
                    v[0] = u0.x; v[1] = u0.y; v[2] = u0.z; v[3] = u0.w;
                    v[4] = u1.x; v[5] = u1.y; v[6] = u1.z; v[7] = u1.w;
                } else {
                    #pragma unroll
                    for (int j = 0; j < 8; ++j) v[j] = (k + j < Kreal) ? src[j] : 0.f;
                }
                bf16x8 p;
                #pragma unroll
                for (int j = 0; j < 8; ++j) p[j] = (__bf16)v[j];
                *(bf16x8*)&As[idx * 8] = p;
            }
        }
        __syncthreads();

        bf16x8 a[4], bfr[2];
        #pragma unroll
        for (int mi = 0; mi < 4; ++mi)
            a[mi] = *(const bf16x8*)&As[(wm + mi * 16 + lr) * 32 + kc];
        #pragma unroll
        for (int ni = 0; ni < 2; ++ni)
            bfr[ni] = *(const bf16x8*)&Bs[(wn + ni * 16 + lr) * 32 + kc];
        #pragma unroll
        for (int mi = 0; mi < 4; ++mi)
            #pragma unroll
            for (int ni = 0; ni < 2; ++ni)
                acc[mi][ni] = __builtin_amdgcn_mfma_f32_16x16x32_bf16(
                    a[mi], bfr[ni], acc[mi][ni], 0, 0, 0);
        __syncthreads();
    }

    #pragma unroll
    for (int ni = 0; ni < 2; ++ni) {
        const int n = bn + wn + ni * 16 + lr;
        const bool nv = (n < Nreal);
        const float gv = nv ? gam[n]  : 0.f;
        const float bv = nv ? bias[n] : 0.f;
        const float ev = nv ? bet[n]  : 0.f;
        #pragma unroll
        for (int mi = 0; mi < 4; ++mi) {
            #pragma unroll
            for (int r = 0; r < 4; ++r) {
                const size_t m = bm + wm + mi * 16 + (lane >> 4) * 4 + r;
                float v = gv * (acc[mi][ni][r] + bv) + ev;
                if (RELU) v = fmaxf(v, 0.f);
                if (CBF16) {
                    ((__bf16*)Cv)[m * ldc + n] = (__bf16)v;
                } else if (nv) {
                    ((float*)Cv)[m * ldc + n] = v;
                }
            }
        }
    }
}

// ---------------------------------------------------------------------------
extern "C" void kernel_launch(void* const* d_in, const int* in_sizes, int n_in,
                              void* d_out, int out_size, void* d_ws, size_t ws_size,
                              hipStream_t stream)
{
    const int*   order_p       = (const int*)d_in[0];
    const int*   x_atom        = (const int*)d_in[1];
    const int*   edge_index    = (const int*)d_in[2];
    const int*   edge_attr     = (const int*)d_in[3];
    const float* atom_tab      = (const float*)d_in[4];
    const float* bond_tab_root = (const float*)d_in[5];
    const float* edge_lin_w    = (const float*)d_in[6];
    const float* edge_lin_b    = (const float*)d_in[7];
    const float* bond_tabs     = (const float*)d_in[8];
    const float* eps           = (const float*)d_in[9];
    const float* w1            = (const float*)d_in[10];
    const float* b1            = (const float*)d_in[11];
    const float* bn1g          = (const float*)d_in[12];
    const float* bn1b          = (const float*)d_in[13];
    const float* w2            = (const float*)d_in[14];
    const float* b2            = (const float*)d_in[15];
    const float* bng           = (const float*)d_in[16];
    const float* bnb           = (const float*)d_in[17];

    float* h = (float*)d_out;   // [65536][300] fp32 master activations

    char* ws = (char*)d_ws;
    __bf16* Ahi_g = (__bf16*)ws;                                // 17,825,792 B
    __bf16* Alo_g = (__bf16*)(ws + 17825792);                   // 17,825,792 B
    __bf16* z1    = (__bf16*)ws;                                // [65536][640]
    __bf16* w1t   = (__bf16*)(ws + 83886080);                   // [5][640][320]
    __bf16* w2t   = (__bf16*)(ws + 83886080 + 2048000);         // [5][320][640]

    prep_w_kernel<<<8000, 256, 0, stream>>>(w1, w2, w1t, w2t);

    adj_kernel<<<NGRAPH, 512, 0, stream>>>(edge_index, edge_attr, bond_tab_root,
                                           edge_lin_w, edge_lin_b, Ahi_g, Alo_g);

    diffuse_mm_kernel<<<NGRAPH, 512, 0, stream>>>(order_p, x_atom, atom_tab,
                                                  Ahi_g, Alo_g, h);

    for (int l = 0; l < NLAYER; ++l) {
        agg_kernel<<<NGRAPH, 1024, 0, stream>>>(edge_index, edge_attr, bond_tabs, eps, l, h);

        gemm_mfma<0, 1, 1><<<5120, 256, 0, stream>>>(
            h, EMB, 300, 10, 10, w1t + (size_t)l * 640 * 320,
            z1, 640, 600, b1 + l * 600, bn1g + l * 600, bn1b + l * 600);

        if (l < NLAYER - 1) {
            gemm_mfma<1, 0, 1><<<2560, 256, 0, stream>>>(
                z1, 640, 640, 20, 5, w2t + (size_t)l * 320 * 640,
                h, EMB, 300, b2 + l * 300, bng + l * 300, bnb + l * 300);
        } else {
            gemm_mfma<1, 0, 0><<<2560, 256, 0, stream>>>(
                z1, 640, 640, 20, 5, w2t + (size_t)l * 320 * 640,
                h, EMB, 300, b2 + l * 300, bng + l * 300, bnb + l * 300);
        }
    }
}

// Round 9
// 1176.180 us; speedup vs baseline: 2.5611x; 2.5611x over previous
//
#include <hip/hip_runtime.h>

#define NGRAPH 512
#define NNODE  128
#define NEDGE  512
#define EMB    300
#define NLAYER 5
#define FA     9
#define FB     3
#define VV     64
#define KPAD   136   // padded K stride (bf16 elems) for A / xT tiles

typedef __bf16 bf16x8 __attribute__((ext_vector_type(8)));
typedef __bf16 bf16x4 __attribute__((ext_vector_type(4)));
typedef float  f32x4  __attribute__((ext_vector_type(4)));

__device__ __forceinline__ void gload_lds16(const void* gptr, void* lptr) {
    __builtin_amdgcn_global_load_lds(
        (const __attribute__((address_space(1))) void*)gptr,
        (__attribute__((address_space(3))) void*)lptr, 16, 0, 0);
}

// ---------------------------------------------------------------------------
// Kernel 0: weight prep — transpose w1/w2 to bf16 [N][K] (padded, zeros).
// ---------------------------------------------------------------------------
__global__ __launch_bounds__(256)
void prep_w_kernel(const float* __restrict__ w1, const float* __restrict__ w2,
                   __bf16* __restrict__ w1t, __bf16* __restrict__ w2t)
{
    const int i = blockIdx.x * 256 + threadIdx.x;
    const int T1 = NLAYER * 640 * 320;
    const int T2 = NLAYER * 320 * 640;
    if (i < T1) {
        const int l = i / (640 * 320);
        const int r = i - l * 640 * 320;
        const int n = r / 320, k = r - n * 320;
        float v = (n < 600 && k < 300) ? w1[((size_t)l * 300 + k) * 600 + n] : 0.f;
        w1t[i] = (__bf16)v;
    } else if (i < T1 + T2) {
        const int j = i - T1;
        const int l = j / (320 * 640);
        const int r = j - l * 320 * 640;
        const int n = r / 640, k = r - n * 640;
        float v = (n < 300 && k < 600) ? w2[((size_t)l * 600 + k) * 300 + n] : 0.f;
        w2t[j] = (__bf16)v;
    }
}

// ---------------------------------------------------------------------------
// Kernel 1a: adjacency build (unchanged)
// ---------------------------------------------------------------------------
__global__ __launch_bounds__(512)
void adj_kernel(const int* __restrict__ edge_index,
                const int* __restrict__ edge_attr,
                const float* __restrict__ bond_tab_root,
                const float* __restrict__ edge_lin_w,
                const float* __restrict__ edge_lin_b,
                __bf16* __restrict__ Ahi_g, __bf16* __restrict__ Alo_g)
{
    __shared__ float A[128 * 129];
    __shared__ float ew_s[NEDGE];
    __shared__ int   es[NEDGE];
    __shared__ float rinv[128];
    __shared__ float cinv[128];

    const int tid = threadIdx.x;
    const int g   = blockIdx.x;
    int* Ai = (int*)A;

    for (int e = tid; e < NEDGE; e += 512) {
        int r = edge_index[(g * 2 + 0) * NEDGE + e];
        int c = edge_index[(g * 2 + 1) * NEDGE + e];
        es[e] = r | (c << 8);
    }
    for (int i = tid; i < 128 * 129; i += 512) Ai[i] = -1;
    __syncthreads();

    {
        const int wave = tid >> 6, lane = tid & 63;
        const float elb = edge_lin_b[0];
        for (int e = wave * 64; e < wave * 64 + 64; ++e) {
            const int base = (g * NEDGE + e) * 3;
            const int a0 = edge_attr[base + 0];
            const int a1 = edge_attr[base + 1];
            const int a2 = edge_attr[base + 2];
            const float* t0 = bond_tab_root + (0 * VV + a0) * EMB;
            const float* t1 = bond_tab_root + (1 * VV + a1) * EMB;
            const float* t2 = bond_tab_root + (2 * VV + a2) * EMB;
            float acc = 0.f;
            for (int d = lane; d < EMB; d += 64)
                acc += (t0[d] + t1[d] + t2[d]) * edge_lin_w[d];
            #pragma unroll
            for (int off = 32; off > 0; off >>= 1) acc += __shfl_xor(acc, off, 64);
            if (lane == 0) ew_s[e] = 1.f / (1.f + expf(-(acc + elb)));
        }
    }
    for (int e = tid; e < NEDGE; e += 512) {
        int r = es[e] & 255, c = es[e] >> 8;
        atomicMax(&Ai[r * 129 + c], e);
        atomicMax(&Ai[c * 129 + r], 512 + e);
    }
    __syncthreads();
    for (int i = tid; i < 128 * 129; i += 512) {
        int p = Ai[i];
        A[i] = (p < 0) ? 0.f : ew_s[p & 511];
    }
    __syncthreads();
    if (tid < 128) A[tid * 129 + tid] += 1.f;
    __syncthreads();
    if (tid < 128) {
        float rs = 0.f, cs = 0.f;
        for (int j = 0; j < 128; ++j) { rs += A[tid * 129 + j]; cs += A[j * 129 + tid]; }
        rinv[tid] = 1.f / sqrtf(rs);
        cinv[tid] = 1.f / sqrtf(cs);
    }
    __syncthreads();
    for (int i = tid; i < 128 * KPAD; i += 512) {
        const int m = i / KPAD, k = i - m * KPAD;
        float v = (k < 128) ? A[m * 129 + k] * cinv[m] * rinv[k] : 0.f;
        __bf16 hi = (__bf16)v;
        Ahi_g[(size_t)g * 128 * KPAD + i] = hi;
        Alo_g[(size_t)g * 128 * KPAD + i] = (__bf16)(v - (float)hi);
    }
}

// ---------------------------------------------------------------------------
// Kernel 1b: diffusion via MFMA with split-bf16 (unchanged)
// ---------------------------------------------------------------------------
__global__ __launch_bounds__(512)
void diffuse_mm_kernel(const int* __restrict__ order_p,
                       const int* __restrict__ x_atom,
                       const float* __restrict__ atom_tab,
                       const __bf16* __restrict__ Ahi_g,
                       const __bf16* __restrict__ Alo_g,
                       float* __restrict__ h)
{
    __shared__ __bf16 Ahi[128 * KPAD];
    __shared__ __bf16 Alo[128 * KPAD];
    __shared__ __bf16 xt[4 * 64 * KPAD];
    __shared__ int    xat[128 * FA];

    const int tid  = threadIdx.x;
    const int g    = blockIdx.x;
    const int lane = tid & 63;
    const int wid  = tid >> 6;
    const int wm   = (wid >> 1) * 32;
    const int wn   = (wid & 1) * 32;
    const int lr   = lane & 15;
    const int q4   = (lane >> 4) * 4;
    const int kc   = (lane >> 4) * 8;

    for (int idx = tid; idx < 128 * KPAD / 8; idx += 512) {
        gload_lds16(Ahi_g + (size_t)g * 128 * KPAD + idx * 8, (char*)Ahi + idx * 16);
        gload_lds16(Alo_g + (size_t)g * 128 * KPAD + idx * 8, (char*)Alo + idx * 16);
    }
    for (int i = tid; i < 128 * FA; i += 512) xat[i] = x_atom[g * 128 * FA + i];
    __syncthreads();

    const int   ord    = order_p[0];
    const float yscale = 1.f / (float)(ord + 1);

    for (int cb = 0; cb < 5; ++cb) {
        const int dbase = cb * 64;

        float yacc[2][2][4];
        #pragma unroll
        for (int mi = 0; mi < 2; ++mi) {
            #pragma unroll
            for (int ni = 0; ni < 2; ++ni) {
                const int n_ = wn + ni * 16 + lr;
                const int d  = dbase + n_;
                #pragma unroll
                for (int r = 0; r < 4; ++r) {
                    const int m_ = wm + mi * 16 + q4 + r;
                    float v = 0.f;
                    if (d < EMB) {
                        #pragma unroll
                        for (int f = 0; f < FA; ++f)
                            v += atom_tab[(size_t)((f << 6) + xat[m_ * FA + f]) * EMB + d];
                        v *= 0.8f;
                    }
                    yacc[mi][ni][r] = v;
                    __bf16 hi = (__bf16)v;
                    xt[0 * 64 * KPAD + n_ * KPAD + m_] = hi;
                    xt[1 * 64 * KPAD + n_ * KPAD + m_] = (__bf16)(v - (float)hi);
                }
            }
        }
        __syncthreads();

        int curbuf = 0;
        for (int o = 0; o < ord; ++o) {
            const __bf16* xh = xt + (curbuf * 2 + 0) * 64 * KPAD;
            const __bf16* xl = xt + (curbuf * 2 + 1) * 64 * KPAD;
            f32x4 racc[2][2];
            #pragma unroll
            for (int mi = 0; mi < 2; ++mi)
                #pragma unroll
                for (int ni = 0; ni < 2; ++ni) racc[mi][ni] = (f32x4){0.f, 0.f, 0.f, 0.f};

            #pragma unroll
            for (int ks = 0; ks < 4; ++ks) {
                const int k0 = ks * 32 + kc;
                bf16x8 ah[2], al[2], bh[2], bl[2];
                #pragma unroll
                for (int mi = 0; mi < 2; ++mi) {
                    ah[mi] = *(const bf16x8*)&Ahi[(wm + mi * 16 + lr) * KPAD + k0];
                    al[mi] = *(const bf16x8*)&Alo[(wm + mi * 16 + lr) * KPAD + k0];
                }
                #pragma unroll
                for (int ni = 0; ni < 2; ++ni) {
                    bh[ni] = *(const bf16x8*)&xh[(wn + ni * 16 + lr) * KPAD + k0];
                    bl[ni] = *(const bf16x8*)&xl[(wn + ni * 16 + lr) * KPAD + k0];
                }
                #pragma unroll
                for (int mi = 0; mi < 2; ++mi) {
                    #pragma unroll
                    for (int ni = 0; ni < 2; ++ni) {
                        racc[mi][ni] = __builtin_amdgcn_mfma_f32_16x16x32_bf16(
                            ah[mi], bh[ni], racc[mi][ni], 0, 0, 0);
                        racc[mi][ni] = __builtin_amdgcn_mfma_f32_16x16x32_bf16(
                            ah[mi], bl[ni], racc[mi][ni], 0, 0, 0);
                        racc[mi][ni] = __builtin_amdgcn_mfma_f32_16x16x32_bf16(
                            al[mi], bh[ni], racc[mi][ni], 0, 0, 0);
                    }
                }
            }

            __bf16* nh = xt + ((curbuf ^ 1) * 2 + 0) * 64 * KPAD;
            __bf16* nl = xt + ((curbuf ^ 1) * 2 + 1) * 64 * KPAD;
            #pragma unroll
            for (int mi = 0; mi < 2; ++mi) {
                #pragma unroll
                for (int ni = 0; ni < 2; ++ni) {
                    const int n_ = wn + ni * 16 + lr;
                    const int mbase = wm + mi * 16 + q4;
                    bf16x4 hv, lv;
                    #pragma unroll
                    for (int r = 0; r < 4; ++r) {
                        const float v = racc[mi][ni][r];
                        yacc[mi][ni][r] += v;
                        __bf16 hi = (__bf16)v;
                        hv[r] = hi;
                        lv[r] = (__bf16)(v - (float)hi);
                    }
                    *(bf16x4*)&nh[n_ * KPAD + mbase] = hv;
                    *(bf16x4*)&nl[n_ * KPAD + mbase] = lv;
                }
            }
            __syncthreads();
            curbuf ^= 1;
        }

        #pragma unroll
        for (int mi = 0; mi < 2; ++mi) {
            #pragma unroll
            for (int ni = 0; ni < 2; ++ni) {
                const int n_ = wn + ni * 16 + lr;
                const int d  = dbase + n_;
                if (d < EMB) {
                    #pragma unroll
                    for (int r = 0; r < 4; ++r) {
                        const int m_ = wm + mi * 16 + q4 + r;
                        h[(size_t)(g * 128 + m_) * EMB + d] = yacc[mi][ni][r] * yscale;
                    }
                }
            }
        }
    }
}

// ---------------------------------------------------------------------------
// Kernel 2: GIN aggregation, CSR gather, 2 blocks/graph (160-col chunks).
// LDS ~46 KB -> 2 blocks/CU (wave-limited). h snapshot staged as bf16
// (messages only; the (1+eps)h seed stays fp32 from global). Output z is
// written bf16 into zb[65536][320] (K-pad zeroed) = gemm1's A operand.
// ---------------------------------------------------------------------------
__global__ __launch_bounds__(1024)
void agg_kernel(const int* __restrict__ edge_index,
                const int* __restrict__ edge_attr,
                const float* __restrict__ bond_tabs,
                const float* __restrict__ eps_all,
                const int l,
                const float* __restrict__ h,
                __bf16* __restrict__ zb)
{
    __shared__ __bf16         hs[128 * 160];   // 40,960 B (bf16 snapshot chunk)
    __shared__ int            epk[NEDGE];      // src|dst<<7|a0<<14|a1<<20|a2<<26
    __shared__ unsigned short eord[NEDGE];     // edge ids sorted by dst
    __shared__ int            cnt[128];
    __shared__ int            off_[129];
    __shared__ int            fill[128];

    const int tid  = threadIdx.x;
    const int g    = blockIdx.x >> 1;
    const int coff = (blockIdx.x & 1) * 160;   // column chunk: 0..159 / 160..319
    const int wave = tid >> 6, lane = tid & 63;
    const float epl = 1.f + eps_all[l];
    const float* bt = bond_tabs + (size_t)l * FB * VV * EMB;

    if (tid < 128) { cnt[tid] = 0; fill[tid] = 0; }
    __syncthreads();
    if (tid < NEDGE) {
        const int s_ = edge_index[(g * 2 + 0) * NEDGE + tid];
        const int d_ = edge_index[(g * 2 + 1) * NEDGE + tid];
        const int base = (g * NEDGE + tid) * 3;
        epk[tid] = s_ | (d_ << 7) | (edge_attr[base + 0] << 14)
                 | (edge_attr[base + 1] << 20) | (edge_attr[base + 2] << 26);
        atomicAdd(&cnt[d_], 1);
    }
    // stage h chunk as bf16 (cols >= EMB zeroed)
    for (int idx = tid; idx < 128 * 40; idx += 1024) {
        const int r = idx / 40, q = (idx - r * 40) * 4;
        bf16x4 v;
        #pragma unroll
        for (int j = 0; j < 4; ++j) {
            const int d = coff + q + j;
            v[j] = (__bf16)((d < EMB) ? h[(size_t)(g * 128 + r) * EMB + d] : 0.f);
        }
        *(bf16x4*)&hs[r * 160 + q] = v;
    }
    __syncthreads();
    // exclusive prefix scan of cnt[128] on wave 0
    if (tid < 64) {
        const int a = cnt[tid];
        const int b = cnt[64 + tid];
        int ia = a;
        #pragma unroll
        for (int o = 1; o < 64; o <<= 1) {
            int t = __shfl_up(ia, o, 64);
            if (tid >= o) ia += t;
        }
        const int totA = __shfl(ia, 63, 64);
        int ib = b;
        #pragma unroll
        for (int o = 1; o < 64; o <<= 1) {
            int t = __shfl_up(ib, o, 64);
            if (tid >= o) ib += t;
        }
        off_[tid]      = ia - a;
        off_[64 + tid] = totA + ib - b;
        if (tid == 63) off_[128] = totA + ib;
    }
    __syncthreads();
    if (tid < NEDGE) {
        const int d_ = (epk[tid] >> 7) & 127;
        const int pos = off_[d_] + atomicAdd(&fill[d_], 1);
        eord[pos] = (unsigned short)tid;
    }
    __syncthreads();

    const int d0 = lane, d1 = lane + 64, d2 = lane + 128;   // d2 valid lane<32
    const bool r0 = (coff + d0) < EMB;
    const bool r1 = (coff + d1) < EMB;
    const bool r2 = (d2 < 160) && ((coff + d2) < EMB);

    for (int n = wave; n < 128; n += 16) {
        const float* hrow = h + (size_t)(g * 128 + n) * EMB + coff;
        float a0 = r0 ? epl * hrow[d0] : 0.f;
        float a1 = r1 ? epl * hrow[d1] : 0.f;
        float a2 = r2 ? epl * hrow[d2] : 0.f;
        const int eEnd = off_[n + 1];
        for (int ee = off_[n]; ee < eEnd; ++ee) {
            const int p   = epk[eord[ee]];
            const int src = p & 127;
            const float* t0 = bt + ((p >> 14) & 63) * EMB + coff;
            const float* t1 = bt + (64  + ((p >> 20) & 63)) * EMB + coff;
            const float* t2 = bt + (128 + ((p >> 26) & 63)) * EMB + coff;
            if (r0) a0 += fmaxf((float)hs[src * 160 + d0] + t0[d0] + t1[d0] + t2[d0], 0.f);
            if (r1) a1 += fmaxf((float)hs[src * 160 + d1] + t0[d1] + t1[d1] + t2[d1], 0.f);
            if (r2) a2 += fmaxf((float)hs[src * 160 + d2] + t0[d2] + t1[d2] + t2[d2], 0.f);
        }
        __bf16* zrow = zb + (size_t)(g * 128 + n) * 320 + coff;
        zrow[d0] = (__bf16)a0;                 // pad cols get 0
        zrow[d1] = (__bf16)a1;
        if (d2 < 160) zrow[d2] = (__bf16)a2;
    }
}

// ---------------------------------------------------------------------------
// Kernel 3: bf16 MFMA GEMM with XCD-chunk swizzle (unchanged from round 6).
// ---------------------------------------------------------------------------
template <int ABF16, int CBF16, int RELU>
__global__ __launch_bounds__(256)
void gemm_mfma(const void* __restrict__ Av, const int lda, const int Kreal,
               const int nT, const int nBlkN, const __bf16* __restrict__ B,
               void* __restrict__ Cv, const int ldc, const int Nreal,
               const float* __restrict__ bias, const float* __restrict__ gam,
               const float* __restrict__ bet)
{
    __shared__ unsigned short As[128 * 32];
    __shared__ unsigned short Bs[64 * 32];

    const int tid  = threadIdx.x;
    const int nwg  = gridDim.x;
    const int hw   = blockIdx.x;
    const int lg   = (hw & 7) * (nwg >> 3) + (hw >> 3);
    const int bn   = (lg % nBlkN) * 64;
    const int bm   = (lg / nBlkN) * 128;
    const int wid  = tid >> 6;
    const int lane = tid & 63;
    const int wm   = (wid >> 1) * 64;
    const int wn   = (wid & 1) * 32;
    const int lr   = lane & 15;
    const int kc   = (lane >> 4) * 8;
    const int KP   = nT * 32;

    f32x4 acc[4][2];
    #pragma unroll
    for (int mi = 0; mi < 4; ++mi)
        #pragma unroll
        for (int ni = 0; ni < 2; ++ni) acc[mi][ni] = (f32x4){0.f, 0.f, 0.f, 0.f};

    for (int t = 0; t < nT; ++t) {
        const int k0 = t * 32;
        {
            const int n = tid >> 2, k8 = (tid & 3) * 8;
            gload_lds16(B + (size_t)(bn + n) * KP + k0 + k8,
                        (char*)Bs + tid * 16);
        }
        if (ABF16) {
            const __bf16* A = (const __bf16*)Av;
            #pragma unroll
            for (int q = 0; q < 2; ++q) {
                const int idx = q * 256 + tid;
                const int m = idx >> 2, k8 = (idx & 3) * 8;
                gload_lds16(A + (size_t)(bm + m) * lda + k0 + k8,
                            (char*)As + idx * 16);
            }
        } else {
            const float* A = (const float*)Av;
            #pragma unroll
            for (int q = 0; q < 2; ++q) {
                const int idx = q * 256 + tid;
                const int m = idx >> 2;
                const int k = k0 + (idx & 3) * 8;
                const float* src = A + (size_t)(bm + m) * lda + k;
                float v[8];
                if (k + 7 < Kreal) {
                    const float4 u0 = *(const float4*)src;
                    const float4 u1 = *(const float4*)(src + 4);
                    v[0] = u0.x; v[1] = u0.y; v[2] = u0.z; v[3] = u0.w;
                    v[4] = u1.x; v[5] = u1.y; v[6] = u1.z; v[7] = u1.w;
                } else {
                    #pragma unroll
                    for (int j = 0; j < 8; ++j) v[j] = (k + j < Kreal) ? src[j] : 0.f;
                }
                bf16x8 p;
                #pragma unroll
                for (int j = 0; j < 8; ++j) p[j] = (__bf16)v[j];
                *(bf16x8*)&As[idx * 8] = p;
            }
        }
        __syncthreads();

        bf16x8 a[4], bfr[2];
        #pragma unroll
        for (int mi = 0; mi < 4; ++mi)
            a[mi] = *(const bf16x8*)&As[(wm + mi * 16 + lr) * 32 + kc];
        #pragma unroll
        for (int ni = 0; ni < 2; ++ni)
            bfr[ni] = *(const bf16x8*)&Bs[(wn + ni * 16 + lr) * 32 + kc];
        #pragma unroll
        for (int mi = 0; mi < 4; ++mi)
            #pragma unroll
            for (int ni = 0; ni < 2; ++ni)
                acc[mi][ni] = __builtin_amdgcn_mfma_f32_16x16x32_bf16(
                    a[mi], bfr[ni], acc[mi][ni], 0, 0, 0);
        __syncthreads();
    }

    #pragma unroll
    for (int ni = 0; ni < 2; ++ni) {
        const int n = bn + wn + ni * 16 + lr;
        const bool nv = (n < Nreal);
        const float gv = nv ? gam[n]  : 0.f;
        const float bv = nv ? bias[n] : 0.f;
        const float ev = nv ? bet[n]  : 0.f;
        #pragma unroll
        for (int mi = 0; mi < 4; ++mi) {
            #pragma unroll
            for (int r = 0; r < 4; ++r) {
                const size_t m = bm + wm + mi * 16 + (lane >> 4) * 4 + r;
                float v = gv * (acc[mi][ni][r] + bv) + ev;
                if (RELU) v = fmaxf(v, 0.f);
                if (CBF16) {
                    ((__bf16*)Cv)[m * ldc + n] = (__bf16)v;
                } else if (nv) {
                    ((float*)Cv)[m * ldc + n] = v;
                }
            }
        }
    }
}

// ---------------------------------------------------------------------------
extern "C" void kernel_launch(void* const* d_in, const int* in_sizes, int n_in,
                              void* d_out, int out_size, void* d_ws, size_t ws_size,
                              hipStream_t stream)
{
    const int*   order_p       = (const int*)d_in[0];
    const int*   x_atom        = (const int*)d_in[1];
    const int*   edge_index    = (const int*)d_in[2];
    const int*   edge_attr     = (const int*)d_in[3];
    const float* atom_tab      = (const float*)d_in[4];
    const float* bond_tab_root = (const float*)d_in[5];
    const float* edge_lin_w    = (const float*)d_in[6];
    const float* edge_lin_b    = (const float*)d_in[7];
    const float* bond_tabs     = (const float*)d_in[8];
    const float* eps           = (const float*)d_in[9];
    const float* w1            = (const float*)d_in[10];
    const float* b1            = (const float*)d_in[11];
    const float* bn1g          = (const float*)d_in[12];
    const float* bn1b          = (const float*)d_in[13];
    const float* w2            = (const float*)d_in[14];
    const float* b2            = (const float*)d_in[15];
    const float* bng           = (const float*)d_in[16];
    const float* bnb           = (const float*)d_in[17];

    float* h = (float*)d_out;   // [65536][300] fp32 master activations

    char* ws = (char*)d_ws;
    __bf16* Ahi_g = (__bf16*)ws;                                // 17,825,792 B
    __bf16* Alo_g = (__bf16*)(ws + 17825792);                   // 17,825,792 B
    __bf16* z1    = (__bf16*)ws;                                // [65536][640] = 83,886,080 B
    __bf16* w1t   = (__bf16*)(ws + 83886080);                   // [5][640][320] = 2,048,000 B
    __bf16* w2t   = (__bf16*)(ws + 83886080 + 2048000);         // [5][320][640] = 2,048,000 B
    __bf16* zb    = (__bf16*)(ws + 83886080 + 4096000);         // [65536][320] = 41,943,040 B

    prep_w_kernel<<<8000, 256, 0, stream>>>(w1, w2, w1t, w2t);

    adj_kernel<<<NGRAPH, 512, 0, stream>>>(edge_index, edge_attr, bond_tab_root,
                                           edge_lin_w, edge_lin_b, Ahi_g, Alo_g);

    diffuse_mm_kernel<<<NGRAPH, 512, 0, stream>>>(order_p, x_atom, atom_tab,
                                                  Ahi_g, Alo_g, h);

    for (int l = 0; l < NLAYER; ++l) {
        // agg: zb[65536][320] bf16 = (1+eps)h + segsum(relu(h[src]+ee))
        agg_kernel<<<NGRAPH * 2, 1024, 0, stream>>>(
            edge_index, edge_attr, bond_tabs, eps, l, h, zb);

        // gemm1: z1 = relu(bn1(zb @ w1 + b1)); A bf16 via global_load_lds
        gemm_mfma<1, 1, 1><<<5120, 256, 0, stream>>>(
            zb, 320, 320, 10, 10, w1t + (size_t)l * 640 * 320,
            z1, 640, 600, b1 + l * 600, bn1g + l * 600, bn1b + l * 600);

        // gemm2: h = bn(z1 @ w2 + b2), relu except last
        if (l < NLAYER - 1) {
            gemm_mfma<1, 0, 1><<<2560, 256, 0, stream>>>(
                z1, 640, 640, 20, 5, w2t + (size_t)l * 320 * 640,
                h, EMB, 300, b2 + l * 300, bng + l * 300, bnb + l * 300);
        } else {
            gemm_mfma<1, 0, 0><<<2560, 256, 0, stream>>>(
                z1, 640, 640, 20, 5, w2t + (size_t)l * 320 * 640,
                h, EMB, 300, b2 + l * 300, bng + l * 300, bnb + l * 300);
        }
    }
}